// Round 1
// baseline (1353.188 us; speedup 1.0000x reference)
//
#include <hip/hip_runtime.h>
#include <math.h>

#define BB 64
#define SS 8192
#define HH 512
#define CHUNKS 16
#define SCHUNK (SS / CHUNKS)   // 512 rows per chunk

// ---------------------------------------------------------------------------
// Pass 1: per (batch, S-chunk) block. Each wave handles 128 rows:
//   - lanes read one 2KiB row (2x float4 each), dot vs LDS decoder vector
//   - butterfly shuffle-reduce -> score (all lanes)
//   - write raw masked score into the d_out weights region (scratch reuse)
//   - online softmax update of per-wave (m, l, ctx[8]/lane)
// Then waves combine via LDS and the block writes one partial (m,l,ctx[512]).
// ---------------------------------------------------------------------------
__global__ __launch_bounds__(256)
void attn_pass1(const float* __restrict__ dh,   // [B,H]
                const float* __restrict__ eo,   // [B,S,H]
                const int*   __restrict__ mask, // [B,S]
                float* __restrict__ score_out,  // [B,S]  (d_out weights region)
                float* __restrict__ pm,         // [B*CHUNKS]
                float* __restrict__ pl,         // [B*CHUNKS]
                float* __restrict__ pctx)       // [B*CHUNKS, H]
{
    const int chunk = blockIdx.x;
    const int b     = blockIdx.y;
    const int tid   = threadIdx.x;
    const int wave  = tid >> 6;
    const int lane  = tid & 63;

    __shared__ float dh_s[HH];
    __shared__ float wacc[4][HH];
    __shared__ float wm[4], wl[4];

    dh_s[tid]       = dh[b * HH + tid];
    dh_s[tid + 256] = dh[b * HH + tid + 256];
    __syncthreads();

    // per-lane 8-float slice of decoder hidden (h = lane*8 .. lane*8+7)
    const float4* dhv = reinterpret_cast<const float4*>(dh_s) + lane * 2;
    const float4 da = dhv[0];
    const float4 db = dhv[1];

    float m = -INFINITY;
    float l = 0.0f;
    float acc[8] = {0.f, 0.f, 0.f, 0.f, 0.f, 0.f, 0.f, 0.f};

    const int s_end = (chunk + 1) * SCHUNK;
    for (int s = chunk * SCHUNK + wave; s < s_end; s += 4) {
        const size_t row_off = ((size_t)b * SS + s) * (size_t)HH;
        const float4* row = reinterpret_cast<const float4*>(eo + row_off) + lane * 2;
        const float4 e0 = row[0];
        const float4 e1 = row[1];
        const int mk = mask[(size_t)b * SS + s];   // wave-uniform

        float p = e0.x * da.x + e0.y * da.y + e0.z * da.z + e0.w * da.w
                + e1.x * db.x + e1.y * db.y + e1.z * db.z + e1.w * db.w;
        #pragma unroll
        for (int off = 32; off > 0; off >>= 1)
            p += __shfl_xor(p, off, 64);

        if (lane == 0)
            score_out[(size_t)b * SS + s] = mk ? p : -INFINITY;

        if (mk) {                       // wave-uniform branch, no divergence
            const float mnew  = fmaxf(m, p);
            const float scale = __expf(m - mnew);   // 0 when m == -inf
            const float w     = __expf(p - mnew);
            l = l * scale + w;
            acc[0] = acc[0] * scale + w * e0.x;
            acc[1] = acc[1] * scale + w * e0.y;
            acc[2] = acc[2] * scale + w * e0.z;
            acc[3] = acc[3] * scale + w * e0.w;
            acc[4] = acc[4] * scale + w * e1.x;
            acc[5] = acc[5] * scale + w * e1.y;
            acc[6] = acc[6] * scale + w * e1.z;
            acc[7] = acc[7] * scale + w * e1.w;
            m = mnew;
        }
    }

    #pragma unroll
    for (int i = 0; i < 8; i++)
        wacc[wave][lane * 8 + i] = acc[i];
    if (lane == 0) { wm[wave] = m; wl[wave] = l; }
    __syncthreads();

    float M = fmaxf(fmaxf(wm[0], wm[1]), fmaxf(wm[2], wm[3]));
    float s0, s1, s2, s3;
    if (M == -INFINITY) {               // fully-masked chunk (pathological)
        s0 = s1 = s2 = s3 = 0.0f;
    } else {
        s0 = __expf(wm[0] - M);
        s1 = __expf(wm[1] - M);
        s2 = __expf(wm[2] - M);
        s3 = __expf(wm[3] - M);
    }
    const float L = wl[0] * s0 + wl[1] * s1 + wl[2] * s2 + wl[3] * s3;
    const int bc = b * CHUNKS + chunk;
    if (tid == 0) { pm[bc] = M; pl[bc] = L; }
    for (int h = tid; h < HH; h += 256)
        pctx[(size_t)bc * HH + h] =
            wacc[0][h] * s0 + wacc[1][h] * s1 + wacc[2][h] * s2 + wacc[3][h] * s3;
}

// ---------------------------------------------------------------------------
// Pass 2: one block per batch. Merge CHUNKS partials -> context + (M, invL).
// ---------------------------------------------------------------------------
__global__ __launch_bounds__(256)
void attn_pass2(const float* __restrict__ pm,
                const float* __restrict__ pl,
                const float* __restrict__ pctx,
                float* __restrict__ ctx_out,   // [B,H]
                float* __restrict__ Mb,        // [B]
                float* __restrict__ invLb)     // [B]
{
    const int b   = blockIdx.x;
    const int tid = threadIdx.x;

    float mj[CHUNKS];
    float M = -INFINITY;
    #pragma unroll
    for (int j = 0; j < CHUNKS; j++) {
        mj[j] = pm[b * CHUNKS + j];
        M = fmaxf(M, mj[j]);
    }
    float sc[CHUNKS];
    float L = 0.0f;
    #pragma unroll
    for (int j = 0; j < CHUNKS; j++) {
        sc[j] = (mj[j] == -INFINITY) ? 0.0f : __expf(mj[j] - M);
        L += pl[b * CHUNKS + j] * sc[j];
    }
    const float invL = 1.0f / L;

    for (int h = tid; h < HH; h += 256) {
        float c = 0.0f;
        #pragma unroll
        for (int j = 0; j < CHUNKS; j++)
            c += pctx[(size_t)(b * CHUNKS + j) * HH + h] * sc[j];
        ctx_out[b * HH + h] = c * invL;
    }
    if (tid == 0) { Mb[b] = M; invLb[b] = invL; }
}

// ---------------------------------------------------------------------------
// Pass 3: in-place scores -> weights, float4-vectorized.
// ---------------------------------------------------------------------------
__global__ __launch_bounds__(256)
void attn_pass3(float* __restrict__ wts,       // [B,S], in-place
                const float* __restrict__ Mb,
                const float* __restrict__ invLb)
{
    const int idx = blockIdx.x * 256 + threadIdx.x;   // one float4 each
    const int b   = idx >> 11;                        // (idx*4) / S, S=8192
    float4 v = reinterpret_cast<const float4*>(wts)[idx];
    const float M    = Mb[b];
    const float invL = invLb[b];
    v.x = __expf(v.x - M) * invL;
    v.y = __expf(v.y - M) * invL;
    v.z = __expf(v.z - M) * invL;
    v.w = __expf(v.w - M) * invL;
    reinterpret_cast<float4*>(wts)[idx] = v;
}

extern "C" void kernel_launch(void* const* d_in, const int* in_sizes, int n_in,
                              void* d_out, int out_size, void* d_ws, size_t ws_size,
                              hipStream_t stream) {
    const float* dh   = (const float*)d_in[0];   // decoder_hidden [B,H]
    const float* eo   = (const float*)d_in[1];   // encoder_outputs [B,S,H]
    const int*   mask = (const int*)d_in[2];     // src_mask [B,S] (bool->int)

    float* ctx_out = (float*)d_out;              // [B,H]
    float* wts     = (float*)d_out + BB * HH;    // [B,S]

    float* pm    = (float*)d_ws;                         // [B*CHUNKS]
    float* pl    = pm + BB * CHUNKS;                     // [B*CHUNKS]
    float* pctx  = pl + BB * CHUNKS;                     // [B*CHUNKS, H]
    float* Mb    = pctx + (size_t)BB * CHUNKS * HH;      // [B]
    float* invLb = Mb + BB;                              // [B]

    attn_pass1<<<dim3(CHUNKS, BB), 256, 0, stream>>>(dh, eo, mask, wts, pm, pl, pctx);
    attn_pass2<<<BB, 256, 0, stream>>>(pm, pl, pctx, ctx_out, Mb, invLb);
    attn_pass3<<<(BB * SS / 4) / 256, 256, 0, stream>>>(wts, Mb, invLb);
}